// Round 1
// 269.574 us; speedup vs baseline: 1.1458x; 1.1458x over previous
//
#include <hip/hip_runtime.h>
#include <math.h>

#define Bn  65536
#define Dn  512
#define Kn  64
#define H1n 256
#define H2n 128
#define BM  32   // rows per block (2048 blocks, 4 waves each; wave = 2 row-tiles x 5 col-tiles)

typedef short bf16x8 __attribute__((ext_vector_type(8)));
typedef float floatx4 __attribute__((ext_vector_type(4)));

__device__ __forceinline__ unsigned short f2bf(float f) {
    unsigned u = __builtin_bit_cast(unsigned, f);
    u += 0x7FFF + ((u >> 16) & 1);   // round-to-nearest-even
    return (unsigned short)(u >> 16);
}

// ---- prep: fp32 weights -> bf16 FRAGMENT-MAJOR Bf[t][ks][lane][8] ----
// Bf element ((t*KS+ks)*64 + quad*16+lrow)*8 + j  =  W[ks*32+quad*8+j][t*16+lrow]
// ws (ushort elems): W1f @0 (131072, KS=16), Tf @131072 (32768, KS=16),
//                    W2f @163840 (32768, KS=8), W3f @196608 (8192, KS=4)
// partials (float)  @ushort offset 204800 (byte 409600), 8192 entries
__global__ __launch_bounds__(256)
void prep_k(const float* __restrict__ W1, const float* __restrict__ W2,
            const float* __restrict__ W3, const float* __restrict__ Th,
            unsigned short* __restrict__ ws)
{
    const int gid = blockIdx.x * 256 + threadIdx.x;
    if (gid < 131072) {                       // W1 [512][256]
        const int s = gid, k = s >> 8, n = s & 255;
        const int dst = (((n >> 4) * 16 + (k >> 5)) * 64 + ((k >> 3) & 3) * 16 + (n & 15)) * 8 + (k & 7);
        ws[dst] = f2bf(W1[s]);
    } else if (gid < 163840) {                // thetas [512][64]
        const int s = gid - 131072, k = s >> 6, n = s & 63;
        const int dst = 131072 + (((n >> 4) * 16 + (k >> 5)) * 64 + ((k >> 3) & 3) * 16 + (n & 15)) * 8 + (k & 7);
        ws[dst] = f2bf(Th[s]);
    } else if (gid < 196608) {                // W2 [256][128]
        const int s = gid - 163840, k = s >> 7, n = s & 127;
        const int dst = 163840 + (((n >> 4) * 8 + (k >> 5)) * 64 + ((k >> 3) & 3) * 16 + (n & 15)) * 8 + (k & 7);
        ws[dst] = f2bf(W2[s]);
    } else if (gid < 204800) {                // W3 [128][64]
        const int s = gid - 196608, k = s >> 6, n = s & 63;
        const int dst = 196608 + (((n >> 4) * 4 + (k >> 5)) * 64 + ((k >> 3) & 3) * 16 + (n & 15)) * 8 + (k & 7);
        ws[dst] = f2bf(W3[s]);
    }
}

// ---- final reduce: sum 8192 wave partials -> out[0] (no atomics anywhere) ----
__global__ __launch_bounds__(1024)
void reduce_k(const float* __restrict__ p, float* __restrict__ out)
{
    __shared__ float sred[16];
    const int tid = threadIdx.x;
    float s = 0.f;
    #pragma unroll
    for (int i = 0; i < 8; ++i) s += p[tid + i * 1024];
    #pragma unroll
    for (int off = 32; off > 0; off >>= 1) s += __shfl_xor(s, off);
    if ((tid & 63) == 0) sred[tid >> 6] = s;
    __syncthreads();
    if (tid < 64) {
        float v = (tid < 16) ? sred[tid] : 0.f;
        #pragma unroll
        for (int off = 8; off > 0; off >>= 1) v += __shfl_xor(v, off);
        if (tid == 0) out[0] = v * (1.0f / (float)Bn);
    }
}

// LDS 49152 B -> 3 blocks/CU (12 waves/CU):
//  [0,32768):     phase1 xA: 32 rows x 64 chunks(16B), XOR-swizzled
//                 phase2+: xt f32[32][68] @0 (8704), lg f32[32][68] @8704 (8704),
//                          h2A @17408: 32 rows x 16 chunks (8192)
//  [32768,49152): h1A: 32 rows x 32 chunks
__global__ __launch_bounds__(256, 3)
void llp_mfma(const float* __restrict__ x,
              const float* __restrict__ label,
              const float* __restrict__ u,
              const float* __restrict__ b1, const float* __restrict__ b2,
              const float* __restrict__ b3,
              const unsigned short* __restrict__ W1f,
              const unsigned short* __restrict__ Tf,
              const unsigned short* __restrict__ W2f,
              const unsigned short* __restrict__ W3f,
              const int* __restrict__ epoch_p,
              float* __restrict__ partials)
{
    __shared__ char smem[49152];

    const int tid  = threadIdx.x;
    const int row0 = blockIdx.x * BM;
    const int w    = tid >> 6;      // wave 0..3
    const int lane = tid & 63;
    const int lrow = lane & 15;
    const int quad = lane >> 4;

    // ---- prefetch u (8 rows/wave) + labels (hide HBM latency behind staging) ----
    float upf[8], labpf[8];
    #pragma unroll
    for (int rr = 0; rr < 8; ++rr) {
        upf[rr]   = u[(size_t)(row0 + w * 8 + rr) * Kn + lane];
        labpf[rr] = label[row0 + w * 8 + rr];
    }

    // ---- stage x tile: 4096 float4, 16 per thread, coalesced ----
    {
        const float4* xg4 = (const float4*)(x + (size_t)row0 * Dn);
        #pragma unroll
        for (int i = 0; i < 16; ++i) {
            const int f = tid + i * 256;           // float4 idx 0..4095
            const float4 v = xg4[f];
            const int row = f >> 7, c4 = f & 127;  // 128 float4 per row
            const int kb = c4 >> 1, half = c4 & 1;
            ushort4 o;
            o.x = f2bf(v.x); o.y = f2bf(v.y); o.z = f2bf(v.z); o.w = f2bf(v.w);
            *(ushort4*)(smem + ((row * 64 + (kb ^ (row & 7))) << 4) + (half << 3)) = o;
        }
    }
    __syncthreads();

    // ---- phase 1: h1 = relu(x@W1+b1) (4 col tiles/wave) + xt = x@thetas (1 tile) ----
    //      2 row-tiles per wave: each B fragment fetched once, used twice.
    //      Explicit depth-1 software pipeline (double-buffered regs, full unroll).
    const int ct0 = w * 4;
    floatx4 acc[2][5];
    #pragma unroll
    for (int t = 0; t < 4; ++t) {
        const float bv = b1[(ct0 + t) * 16 + lrow];
        acc[0][t] = (floatx4){bv, bv, bv, bv};
        acc[1][t] = (floatx4){bv, bv, bv, bv};
    }
    acc[0][4] = (floatx4){0.f, 0.f, 0.f, 0.f};
    acc[1][4] = (floatx4){0.f, 0.f, 0.f, 0.f};

    bf16x8 aB[2][2], bB[2][5];
    #pragma unroll
    for (int rt = 0; rt < 2; ++rt)
        aB[0][rt] = *(const bf16x8*)(smem +
                        (((rt * 16 + lrow) * 64 + (quad ^ (lrow & 7))) << 4));
    #pragma unroll
    for (int t = 0; t < 4; ++t)
        bB[0][t] = *(const bf16x8*)(W1f + ((((ct0 + t) * 16 + 0) * 64 + lane) << 3));
    bB[0][4] = *(const bf16x8*)(Tf + (((w * 16 + 0) * 64 + lane) << 3));

    #pragma unroll
    for (int ks = 0; ks < 16; ++ks) {
        const int cur = ks & 1, nxt = cur ^ 1;
        if (ks < 15) {
            const int kn = ks + 1;
            #pragma unroll
            for (int rt = 0; rt < 2; ++rt)
                aB[nxt][rt] = *(const bf16x8*)(smem +
                    (((rt * 16 + lrow) * 64 + ((kn * 4 + quad) ^ (lrow & 7))) << 4));
            #pragma unroll
            for (int t = 0; t < 4; ++t)
                bB[nxt][t] = *(const bf16x8*)(W1f + ((((ct0 + t) * 16 + kn) * 64 + lane) << 3));
            bB[nxt][4] = *(const bf16x8*)(Tf + (((w * 16 + kn) * 64 + lane) << 3));
        }
        #pragma unroll
        for (int t = 0; t < 5; ++t) {
            acc[0][t] = __builtin_amdgcn_mfma_f32_16x16x32_bf16(aB[cur][0], bB[cur][t], acc[0][t], 0, 0, 0);
            acc[1][t] = __builtin_amdgcn_mfma_f32_16x16x32_bf16(aB[cur][1], bB[cur][t], acc[1][t], 0, 0, 0);
        }
    }

    // h1 C-layout -> bf16 A-layout @32768
    #pragma unroll
    for (int rt = 0; rt < 2; ++rt) {
        #pragma unroll
        for (int t = 0; t < 4; ++t) {
            const int col = (ct0 + t) * 16 + lrow;
            #pragma unroll
            for (int g = 0; g < 4; ++g) {
                const int orow = rt * 16 + quad * 4 + g;
                *(unsigned short*)(smem + 32768 +
                    ((orow * 32 + ((col >> 3) ^ (orow & 7))) << 4) + ((col & 7) << 1))
                    = f2bf(fmaxf(acc[rt][t][g], 0.0f));
            }
        }
    }
    __syncthreads();   // xA dead; h1A complete

    // xt f32 -> @0 [32][68]
    {
        float* xtf = (float*)smem;
        #pragma unroll
        for (int rt = 0; rt < 2; ++rt)
            #pragma unroll
            for (int g = 0; g < 4; ++g)
                xtf[(rt * 16 + quad * 4 + g) * 68 + w * 16 + lrow] = acc[rt][4][g];
    }

    // ---- h2 = relu(h1@W2+b2): 2 col tiles/wave x 2 row-tiles, pipelined ----
    const int c20 = w * 2;
    floatx4 acc2[2][2];
    #pragma unroll
    for (int i = 0; i < 2; ++i) {
        const float bv = b2[(c20 + i) * 16 + lrow];
        acc2[0][i] = (floatx4){bv, bv, bv, bv};
        acc2[1][i] = (floatx4){bv, bv, bv, bv};
    }
    bf16x8 a2[2][2], b2B[2][2];
    #pragma unroll
    for (int rt = 0; rt < 2; ++rt)
        a2[0][rt] = *(const bf16x8*)(smem + 32768 +
                        (((rt * 16 + lrow) * 32 + (quad ^ (lrow & 7))) << 4));
    #pragma unroll
    for (int i = 0; i < 2; ++i)
        b2B[0][i] = *(const bf16x8*)(W2f + ((((c20 + i) * 8 + 0) * 64 + lane) << 3));

    #pragma unroll
    for (int ks = 0; ks < 8; ++ks) {
        const int cur = ks & 1, nxt = cur ^ 1;
        if (ks < 7) {
            const int kn = ks + 1;
            #pragma unroll
            for (int rt = 0; rt < 2; ++rt)
                a2[nxt][rt] = *(const bf16x8*)(smem + 32768 +
                    (((rt * 16 + lrow) * 32 + ((kn * 4 + quad) ^ (lrow & 7))) << 4));
            #pragma unroll
            for (int i = 0; i < 2; ++i)
                b2B[nxt][i] = *(const bf16x8*)(W2f + ((((c20 + i) * 8 + kn) * 64 + lane) << 3));
        }
        #pragma unroll
        for (int i = 0; i < 2; ++i) {
            acc2[0][i] = __builtin_amdgcn_mfma_f32_16x16x32_bf16(a2[cur][0], b2B[cur][i], acc2[0][i], 0, 0, 0);
            acc2[1][i] = __builtin_amdgcn_mfma_f32_16x16x32_bf16(a2[cur][1], b2B[cur][i], acc2[1][i], 0, 0, 0);
        }
    }
    #pragma unroll
    for (int rt = 0; rt < 2; ++rt) {
        #pragma unroll
        for (int i = 0; i < 2; ++i) {
            const int col = (c20 + i) * 16 + lrow;
            #pragma unroll
            for (int g = 0; g < 4; ++g) {
                const int orow = rt * 16 + quad * 4 + g;
                *(unsigned short*)(smem + 17408 +
                    ((orow * 16 + ((col >> 3) ^ (orow & 7))) << 4) + ((col & 7) << 1))
                    = f2bf(fmaxf(acc2[rt][i][g], 0.0f));
            }
        }
    }
    __syncthreads();   // h2A complete (xt stores also done)

    // ---- logits = h2@W3+b3: 1 col tile/wave x 2 row-tiles ----
    floatx4 acc3[2];
    {
        const float bv = b3[w * 16 + lrow];
        acc3[0] = (floatx4){bv, bv, bv, bv};
        acc3[1] = (floatx4){bv, bv, bv, bv};
    }
    #pragma unroll
    for (int ks = 0; ks < 4; ++ks) {
        const bf16x8 bb = *(const bf16x8*)(W3f + (((w * 4 + ks) * 64 + lane) << 3));
        #pragma unroll
        for (int rt = 0; rt < 2; ++rt) {
            const bf16x8 aa = *(const bf16x8*)(smem + 17408 +
                (((rt * 16 + lrow) * 16 + ((ks * 4 + quad) ^ (lrow & 7))) << 4));
            acc3[rt] = __builtin_amdgcn_mfma_f32_16x16x32_bf16(aa, bb, acc3[rt], 0, 0, 0);
        }
    }
    {
        float* lgf = (float*)(smem + 8704);   // [32][68]
        #pragma unroll
        for (int rt = 0; rt < 2; ++rt)
            #pragma unroll
            for (int g = 0; g < 4; ++g)
                lgf[(rt * 16 + quad * 4 + g) * 68 + w * 16 + lrow] = acc3[rt][g];
    }
    __syncthreads();

    // ---- softmax + weighted sum + loss partial: wave w -> rows w*8..+7 ----
    {
        const float* xtf = (const float*)smem;
        const float* lgf = (const float*)(smem + 8704);
        const int ep = *epoch_p;
        const float tmp = 10.0f * powf(0.01f, (float)ep * 0.001f);
        const float inv_temp = 1.0f / fmaxf(0.1f, tmp);

        float partial = 0.0f;
        #pragma unroll
        for (int rr = 0; rr < 8; ++rr) {
            const int rw = w * 8 + rr;
            const float g = -logf(-logf(upf[rr]));
            float s = (lgf[rw * 68 + lane] + g) * inv_temp;
            float m = s;
            #pragma unroll
            for (int off = 32; off > 0; off >>= 1)
                m = fmaxf(m, __shfl_xor(m, off));
            const float e = expf(s - m);
            float sum = e;
            #pragma unroll
            for (int off = 32; off > 0; off >>= 1)
                sum += __shfl_xor(sum, off);
            float v = (e / sum) * xtf[rw * 68 + lane];
            #pragma unroll
            for (int off = 32; off > 0; off >>= 1)
                v += __shfl_xor(v, off);
            const float diff = v - labpf[rr];   // same value on all lanes
            partial = fmaf(diff, diff, partial);
        }
        if (lane == 0)
            partials[blockIdx.x * 4 + w] = partial;   // private slot, no atomic
    }
}

extern "C" void kernel_launch(void* const* d_in, const int* in_sizes, int n_in,
                              void* d_out, int out_size, void* d_ws, size_t ws_size,
                              hipStream_t stream) {
    const float* x      = (const float*)d_in[0];
    const float* label  = (const float*)d_in[1];
    const float* u      = (const float*)d_in[2];
    const float* W1     = (const float*)d_in[3];
    const float* b1     = (const float*)d_in[4];
    const float* W2     = (const float*)d_in[5];
    const float* b2     = (const float*)d_in[6];
    const float* W3     = (const float*)d_in[7];
    const float* b3     = (const float*)d_in[8];
    const float* thetas = (const float*)d_in[9];
    const int*   epoch  = (const int*)d_in[10];
    float* out = (float*)d_out;

    unsigned short* wsb = (unsigned short*)d_ws;
    float* partials = (float*)(wsb + 204800);    // byte offset 409600

    prep_k<<<800, 256, 0, stream>>>(W1, W2, W3, thetas, wsb);
    llp_mfma<<<Bn / BM, 256, 0, stream>>>(x, label, u, b1, b2, b3,
                                          wsb, wsb + 131072, wsb + 163840, wsb + 196608,
                                          epoch, partials);
    reduce_k<<<1, 1024, 0, stream>>>(partials, out);
}

// Round 3
// 261.908 us; speedup vs baseline: 1.1793x; 1.0293x over previous
//
#include <hip/hip_runtime.h>
#include <math.h>

#define Bn  65536
#define Dn  512
#define Kn  64
#define H1n 256
#define H2n 128
#define BM  32   // rows per block (2048 blocks, 4 waves; wave = 2 row-tiles x 5 col-tiles)

typedef short bf16x8 __attribute__((ext_vector_type(8)));
typedef float floatx4 __attribute__((ext_vector_type(4)));

__device__ __forceinline__ unsigned short f2bf(float f) {
    unsigned u = __builtin_bit_cast(unsigned, f);
    u += 0x7FFF + ((u >> 16) & 1);   // round-to-nearest-even
    return (unsigned short)(u >> 16);
}

// ---- prep: fp32 weights -> bf16 FRAGMENT-MAJOR Bf[t][ks][lane][8] ----
// Bf element ((t*KS+ks)*64 + quad*16+lrow)*8 + j  =  W[ks*32+quad*8+j][t*16+lrow]
// ws (ushort elems): W1f @0 (131072, KS=16), Tf @131072 (32768, KS=16),
//                    W2f @163840 (32768, KS=8), W3f @196608 (8192, KS=4)
// partials (float)  @byte 409600, 8192 entries
__global__ __launch_bounds__(256)
void prep_k(const float* __restrict__ W1, const float* __restrict__ W2,
            const float* __restrict__ W3, const float* __restrict__ Th,
            unsigned short* __restrict__ ws)
{
    const int gid = blockIdx.x * 256 + threadIdx.x;
    if (gid < 131072) {                       // W1 [512][256]
        const int s = gid, k = s >> 8, n = s & 255;
        const int dst = (((n >> 4) * 16 + (k >> 5)) * 64 + ((k >> 3) & 3) * 16 + (n & 15)) * 8 + (k & 7);
        ws[dst] = f2bf(W1[s]);
    } else if (gid < 163840) {                // thetas [512][64]
        const int s = gid - 131072, k = s >> 6, n = s & 63;
        const int dst = 131072 + (((n >> 4) * 16 + (k >> 5)) * 64 + ((k >> 3) & 3) * 16 + (n & 15)) * 8 + (k & 7);
        ws[dst] = f2bf(Th[s]);
    } else if (gid < 196608) {                // W2 [256][128]
        const int s = gid - 163840, k = s >> 7, n = s & 127;
        const int dst = 163840 + (((n >> 4) * 8 + (k >> 5)) * 64 + ((k >> 3) & 3) * 16 + (n & 15)) * 8 + (k & 7);
        ws[dst] = f2bf(W2[s]);
    } else if (gid < 204800) {                // W3 [128][64]
        const int s = gid - 196608, k = s >> 6, n = s & 63;
        const int dst = 196608 + (((n >> 4) * 4 + (k >> 5)) * 64 + ((k >> 3) & 3) * 16 + (n & 15)) * 8 + (k & 7);
        ws[dst] = f2bf(W3[s]);
    }
}

// ---- final reduce: sum 8192 wave partials -> out[0] (no atomics anywhere) ----
__global__ __launch_bounds__(1024)
void reduce_k(const float* __restrict__ p, float* __restrict__ out)
{
    __shared__ float sred[16];
    const int tid = threadIdx.x;
    float s = 0.f;
    #pragma unroll
    for (int i = 0; i < 8; ++i) s += p[tid + i * 1024];
    #pragma unroll
    for (int off = 32; off > 0; off >>= 1) s += __shfl_xor(s, off);
    if ((tid & 63) == 0) sred[tid >> 6] = s;
    __syncthreads();
    if (tid < 64) {
        float v = (tid < 16) ? sred[tid] : 0.f;
        #pragma unroll
        for (int off = 8; off > 0; off >>= 1) v += __shfl_xor(v, off);
        if (tid == 0) out[0] = v * (1.0f / (float)Bn);
    }
}

// LDS 32768 B -> 4 blocks/CU (16 waves/CU):
//  phase 0/1:   xA @0: 32 rows x 64 chunks(16B), XOR-swizzled          (32768)
//  post-p1:     h1A @0: 32 rows x 32 chunks                            (16384)
//               xt f32[32][64] @16384                                  ( 8192)
//  phase 2 out: h2A @24576: 32 rows x 16 chunks                        ( 8192)
//  phase 3 out: lg f32[32][64] @0  (h1A dead)                          ( 8192)
__global__ __launch_bounds__(256, 4)
void llp_mfma(const float* __restrict__ x,
              const float* __restrict__ label,
              const float* __restrict__ u,
              const float* __restrict__ b1, const float* __restrict__ b2,
              const float* __restrict__ b3,
              const unsigned short* __restrict__ W1f,
              const unsigned short* __restrict__ Tf,
              const unsigned short* __restrict__ W2f,
              const unsigned short* __restrict__ W3f,
              const int* __restrict__ epoch_p,
              float* __restrict__ partials)
{
    __shared__ char smem[32768];

    const int tid  = threadIdx.x;
    const int row0 = blockIdx.x * BM;
    const int w    = tid >> 6;      // wave 0..3
    const int lane = tid & 63;
    const int lrow = lane & 15;
    const int quad = lane >> 4;

    // ---- prefetch u (8 rows/wave) + labels (hide HBM latency behind staging) ----
    float upf[8], labpf[8];
    #pragma unroll
    for (int rr = 0; rr < 8; ++rr) {
        upf[rr]   = u[(size_t)(row0 + w * 8 + rr) * Kn + lane];
        labpf[rr] = label[row0 + w * 8 + rr];
    }

    // ---- stage x tile: 4096 float4, 16 per thread, coalesced ----
    {
        const float4* xg4 = (const float4*)(x + (size_t)row0 * Dn);
        #pragma unroll
        for (int i = 0; i < 16; ++i) {
            const int f = tid + i * 256;           // float4 idx 0..4095
            const float4 v = xg4[f];
            const int row = f >> 7, c4 = f & 127;  // 128 float4 per row
            const int kb = c4 >> 1, half = c4 & 1;
            ushort4 o;
            o.x = f2bf(v.x); o.y = f2bf(v.y); o.z = f2bf(v.z); o.w = f2bf(v.w);
            *(ushort4*)(smem + ((row * 64 + (kb ^ (row & 7))) << 4) + (half << 3)) = o;
        }
    }
    __syncthreads();

    // ---- phase 1: h1 = relu(x@W1+b1) (4 col tiles/wave) + xt = x@thetas (1 tile) ----
    //      2 row-tiles per wave; depth-1 software pipeline (full unroll, static idx).
    const int ct0 = w * 4;
    floatx4 acc[2][5];
    #pragma unroll
    for (int t = 0; t < 4; ++t) {
        const float bv = b1[(ct0 + t) * 16 + lrow];
        acc[0][t] = (floatx4){bv, bv, bv, bv};
        acc[1][t] = (floatx4){bv, bv, bv, bv};
    }
    acc[0][4] = (floatx4){0.f, 0.f, 0.f, 0.f};
    acc[1][4] = (floatx4){0.f, 0.f, 0.f, 0.f};

    bf16x8 aB[2][2], bB[2][5];
    #pragma unroll
    for (int rt = 0; rt < 2; ++rt)
        aB[0][rt] = *(const bf16x8*)(smem +
                        (((rt * 16 + lrow) * 64 + (quad ^ (lrow & 7))) << 4));
    #pragma unroll
    for (int t = 0; t < 4; ++t)
        bB[0][t] = *(const bf16x8*)(W1f + ((((ct0 + t) * 16 + 0) * 64 + lane) << 3));
    bB[0][4] = *(const bf16x8*)(Tf + (((w * 16 + 0) * 64 + lane) << 3));

    #pragma unroll
    for (int ks = 0; ks < 16; ++ks) {
        const int cur = ks & 1, nxt = cur ^ 1;
        if (ks < 15) {
            const int kn = ks + 1;
            #pragma unroll
            for (int rt = 0; rt < 2; ++rt)
                aB[nxt][rt] = *(const bf16x8*)(smem +
                    (((rt * 16 + lrow) * 64 + ((kn * 4 + quad) ^ (lrow & 7))) << 4));
            #pragma unroll
            for (int t = 0; t < 4; ++t)
                bB[nxt][t] = *(const bf16x8*)(W1f + ((((ct0 + t) * 16 + kn) * 64 + lane) << 3));
            bB[nxt][4] = *(const bf16x8*)(Tf + (((w * 16 + kn) * 64 + lane) << 3));
        }
        #pragma unroll
        for (int t = 0; t < 5; ++t) {
            acc[0][t] = __builtin_amdgcn_mfma_f32_16x16x32_bf16(aB[cur][0], bB[cur][t], acc[0][t], 0, 0, 0);
            acc[1][t] = __builtin_amdgcn_mfma_f32_16x16x32_bf16(aB[cur][1], bB[cur][t], acc[1][t], 0, 0, 0);
        }
    }
    __syncthreads();   // all xA reads complete -> @0 reusable for h1A

    // h1 C-layout -> bf16 A-layout @0 ; xt f32 -> @16384 [32][64]
    #pragma unroll
    for (int rt = 0; rt < 2; ++rt) {
        #pragma unroll
        for (int t = 0; t < 4; ++t) {
            const int col = (ct0 + t) * 16 + lrow;
            #pragma unroll
            for (int g = 0; g < 4; ++g) {
                const int orow = rt * 16 + quad * 4 + g;
                *(unsigned short*)(smem +
                    ((orow * 32 + ((col >> 3) ^ (orow & 7))) << 4) + ((col & 7) << 1))
                    = f2bf(fmaxf(acc[rt][t][g], 0.0f));
            }
        }
    }
    {
        float* xtf = (float*)(smem + 16384);
        #pragma unroll
        for (int rt = 0; rt < 2; ++rt)
            #pragma unroll
            for (int g = 0; g < 4; ++g)
                xtf[(rt * 16 + quad * 4 + g) * 64 + w * 16 + lrow] = acc[rt][4][g];
    }
    __syncthreads();   // h1A + xt ready

    // ---- h2 = relu(h1@W2+b2): 2 col tiles/wave x 2 row-tiles, pipelined ----
    const int c20 = w * 2;
    floatx4 acc2[2][2];
    #pragma unroll
    for (int i = 0; i < 2; ++i) {
        const float bv = b2[(c20 + i) * 16 + lrow];
        acc2[0][i] = (floatx4){bv, bv, bv, bv};
        acc2[1][i] = (floatx4){bv, bv, bv, bv};
    }
    bf16x8 a2[2][2], b2B[2][2];
    #pragma unroll
    for (int rt = 0; rt < 2; ++rt)
        a2[0][rt] = *(const bf16x8*)(smem +
                        (((rt * 16 + lrow) * 32 + (quad ^ (lrow & 7))) << 4));
    #pragma unroll
    for (int i = 0; i < 2; ++i)
        b2B[0][i] = *(const bf16x8*)(W2f + ((((c20 + i) * 8 + 0) * 64 + lane) << 3));

    #pragma unroll
    for (int ks = 0; ks < 8; ++ks) {
        const int cur = ks & 1, nxt = cur ^ 1;
        if (ks < 7) {
            const int kn = ks + 1;
            #pragma unroll
            for (int rt = 0; rt < 2; ++rt)
                a2[nxt][rt] = *(const bf16x8*)(smem +
                    (((rt * 16 + lrow) * 32 + ((kn * 4 + quad) ^ (lrow & 7))) << 4));
            #pragma unroll
            for (int i = 0; i < 2; ++i)
                b2B[nxt][i] = *(const bf16x8*)(W2f + ((((c20 + i) * 8 + kn) * 64 + lane) << 3));
        }
        #pragma unroll
        for (int i = 0; i < 2; ++i) {
            acc2[0][i] = __builtin_amdgcn_mfma_f32_16x16x32_bf16(a2[cur][0], b2B[cur][i], acc2[0][i], 0, 0, 0);
            acc2[1][i] = __builtin_amdgcn_mfma_f32_16x16x32_bf16(a2[cur][1], b2B[cur][i], acc2[1][i], 0, 0, 0);
        }
    }
    // h2A @24576 (region dead since bar2; nobody reads it before next barrier)
    #pragma unroll
    for (int rt = 0; rt < 2; ++rt) {
        #pragma unroll
        for (int i = 0; i < 2; ++i) {
            const int col = (c20 + i) * 16 + lrow;
            #pragma unroll
            for (int g = 0; g < 4; ++g) {
                const int orow = rt * 16 + quad * 4 + g;
                *(unsigned short*)(smem + 24576 +
                    ((orow * 16 + ((col >> 3) ^ (orow & 7))) << 4) + ((col & 7) << 1))
                    = f2bf(fmaxf(acc2[rt][i][g], 0.0f));
            }
        }
    }
    __syncthreads();   // h2A ready; h1A reads done -> @0 free for lg

    // ---- logits = h2@W3+b3: 1 col tile/wave x 2 row-tiles ----
    floatx4 acc3[2];
    {
        const float bv = b3[w * 16 + lrow];
        acc3[0] = (floatx4){bv, bv, bv, bv};
        acc3[1] = (floatx4){bv, bv, bv, bv};
    }
    #pragma unroll
    for (int ks = 0; ks < 4; ++ks) {
        const bf16x8 bb = *(const bf16x8*)(W3f + (((w * 4 + ks) * 64 + lane) << 3));
        #pragma unroll
        for (int rt = 0; rt < 2; ++rt) {
            const bf16x8 aa = *(const bf16x8*)(smem + 24576 +
                (((rt * 16 + lrow) * 16 + ((ks * 4 + quad) ^ (lrow & 7))) << 4));
            acc3[rt] = __builtin_amdgcn_mfma_f32_16x16x32_bf16(aa, bb, acc3[rt], 0, 0, 0);
        }
    }
    {
        float* lgf = (float*)smem;   // [32][64] @0
        #pragma unroll
        for (int rt = 0; rt < 2; ++rt)
            #pragma unroll
            for (int g = 0; g < 4; ++g)
                lgf[(rt * 16 + quad * 4 + g) * 64 + w * 16 + lrow] = acc3[rt][g];
    }
    __syncthreads();

    // ---- softmax + weighted sum + loss partial: wave w -> rows w*8..+7 ----
    {
        const float* lgf = (const float*)smem;
        const float* xtf = (const float*)(smem + 16384);
        const int ep = *epoch_p;
        const float tmp = 10.0f * powf(0.01f, (float)ep * 0.001f);
        const float inv_temp = 1.0f / fmaxf(0.1f, tmp);

        float partial = 0.0f;
        #pragma unroll
        for (int rr = 0; rr < 8; ++rr) {
            const int rw = w * 8 + rr;
            const float g = -logf(-logf(upf[rr]));
            float s = (lgf[rw * 64 + lane] + g) * inv_temp;
            float m = s;
            #pragma unroll
            for (int off = 32; off > 0; off >>= 1)
                m = fmaxf(m, __shfl_xor(m, off));
            const float e = expf(s - m);
            float sum = e;
            #pragma unroll
            for (int off = 32; off > 0; off >>= 1)
                sum += __shfl_xor(sum, off);
            float v = (e / sum) * xtf[rw * 64 + lane];
            #pragma unroll
            for (int off = 32; off > 0; off >>= 1)
                v += __shfl_xor(v, off);
            const float diff = v - labpf[rr];   // same value on all lanes
            partial = fmaf(diff, diff, partial);
        }
        if (lane == 0)
            partials[blockIdx.x * 4 + w] = partial;   // private slot, no atomic
    }
}

extern "C" void kernel_launch(void* const* d_in, const int* in_sizes, int n_in,
                              void* d_out, int out_size, void* d_ws, size_t ws_size,
                              hipStream_t stream) {
    const float* x      = (const float*)d_in[0];
    const float* label  = (const float*)d_in[1];
    const float* u      = (const float*)d_in[2];
    const float* W1     = (const float*)d_in[3];
    const float* b1     = (const float*)d_in[4];
    const float* W2     = (const float*)d_in[5];
    const float* b2     = (const float*)d_in[6];
    const float* W3     = (const float*)d_in[7];
    const float* b3     = (const float*)d_in[8];
    const float* thetas = (const float*)d_in[9];
    const int*   epoch  = (const int*)d_in[10];
    float* out = (float*)d_out;

    unsigned short* wsb = (unsigned short*)d_ws;
    float* partials = (float*)((char*)d_ws + 409600);

    prep_k<<<800, 256, 0, stream>>>(W1, W2, W3, thetas, wsb);
    llp_mfma<<<Bn / BM, 256, 0, stream>>>(x, label, u, b1, b2, b3,
                                          wsb, wsb + 131072, wsb + 163840, wsb + 196608,
                                          epoch, partials);
    reduce_k<<<1, 1024, 0, stream>>>(partials, out);
}

// Round 4
// 261.881 us; speedup vs baseline: 1.1795x; 1.0001x over previous
//
#include <hip/hip_runtime.h>
#include <math.h>

#define Bn  65536
#define Dn  512
#define Kn  64
#define H1n 256
#define H2n 128
#define BM  32   // rows per block (2048 blocks, 4 waves; wave = 2 row-tiles x 5 col-tiles)

typedef short bf16x8 __attribute__((ext_vector_type(8)));
typedef float floatx4 __attribute__((ext_vector_type(4)));

__device__ __forceinline__ unsigned short f2bf(float f) {
    unsigned u = __builtin_bit_cast(unsigned, f);
    u += 0x7FFF + ((u >> 16) & 1);   // round-to-nearest-even
    return (unsigned short)(u >> 16);
}

// packed f32x2 -> bf16x2 (RTNE), single VALU op
__device__ __forceinline__ unsigned cvt_pk_bf16(float lo, float hi) {
    unsigned r;
    asm("v_cvt_pk_bf16_f32 %0, %1, %2" : "=v"(r) : "v"(lo), "v"(hi));
    return r;
}

// ---- prep: fp32 weights -> bf16 FRAGMENT-MAJOR Bf[t][ks][lane][8] ----
// Bf element ((t*KS+ks)*64 + quad*16+lrow)*8 + j  =  W[ks*32+quad*8+j][t*16+lrow]
// ws (ushort elems): W1f @0 (131072, KS=16), Tf @131072 (32768, KS=16),
//                    W2f @163840 (32768, KS=8), W3f @196608 (8192, KS=4)
// partials (float)  @byte 409600, 8192 entries
__global__ __launch_bounds__(256)
void prep_k(const float* __restrict__ W1, const float* __restrict__ W2,
            const float* __restrict__ W3, const float* __restrict__ Th,
            unsigned short* __restrict__ ws)
{
    const int gid = blockIdx.x * 256 + threadIdx.x;
    if (gid < 131072) {                       // W1 [512][256]
        const int s = gid, k = s >> 8, n = s & 255;
        const int dst = (((n >> 4) * 16 + (k >> 5)) * 64 + ((k >> 3) & 3) * 16 + (n & 15)) * 8 + (k & 7);
        ws[dst] = f2bf(W1[s]);
    } else if (gid < 163840) {                // thetas [512][64]
        const int s = gid - 131072, k = s >> 6, n = s & 63;
        const int dst = 131072 + (((n >> 4) * 16 + (k >> 5)) * 64 + ((k >> 3) & 3) * 16 + (n & 15)) * 8 + (k & 7);
        ws[dst] = f2bf(Th[s]);
    } else if (gid < 196608) {                // W2 [256][128]
        const int s = gid - 163840, k = s >> 7, n = s & 127;
        const int dst = 163840 + (((n >> 4) * 8 + (k >> 5)) * 64 + ((k >> 3) & 3) * 16 + (n & 15)) * 8 + (k & 7);
        ws[dst] = f2bf(W2[s]);
    } else if (gid < 204800) {                // W3 [128][64]
        const int s = gid - 196608, k = s >> 6, n = s & 63;
        const int dst = 196608 + (((n >> 4) * 4 + (k >> 5)) * 64 + ((k >> 3) & 3) * 16 + (n & 15)) * 8 + (k & 7);
        ws[dst] = f2bf(W3[s]);
    }
}

// ---- final reduce: sum 8192 wave partials -> out[0] (no atomics anywhere) ----
__global__ __launch_bounds__(1024)
void reduce_k(const float* __restrict__ p, float* __restrict__ out)
{
    __shared__ float sred[16];
    const int tid = threadIdx.x;
    float s = 0.f;
    #pragma unroll
    for (int i = 0; i < 8; ++i) s += p[tid + i * 1024];
    #pragma unroll
    for (int off = 32; off > 0; off >>= 1) s += __shfl_xor(s, off);
    if ((tid & 63) == 0) sred[tid >> 6] = s;
    __syncthreads();
    if (tid < 64) {
        float v = (tid < 16) ? sred[tid] : 0.f;
        #pragma unroll
        for (int off = 8; off > 0; off >>= 1) v += __shfl_xor(v, off);
        if (tid == 0) out[0] = v * (1.0f / (float)Bn);
    }
}

// LDS 32768 B -> 4 blocks/CU (16 waves/CU):
//  phase 0/1:   xA @0: 32 rows x 64 chunks(16B), XOR-swizzled          (32768)
//  post-p1:     h1A @0: 32 rows x 32 chunks                            (16384)
//               xt f32[32][64] @16384 (col ^ quad<<4 bank swizzle)     ( 8192)
//  phase 2 out: h2A @24576: 32 rows x 16 chunks                        ( 8192)
//  phase 3 out: lg f32[32][64] @0  (h1A dead)                          ( 8192)
__global__ __launch_bounds__(256, 4)
void llp_mfma(const float* __restrict__ x,
              const float* __restrict__ label,
              const float* __restrict__ u,
              const float* __restrict__ b1, const float* __restrict__ b2,
              const float* __restrict__ b3,
              const unsigned short* __restrict__ W1f,
              const unsigned short* __restrict__ Tf,
              const unsigned short* __restrict__ W2f,
              const unsigned short* __restrict__ W3f,
              const int* __restrict__ epoch_p,
              float* __restrict__ partials)
{
    __shared__ char smem[32768];

    const int tid  = threadIdx.x;
    const int row0 = blockIdx.x * BM;
    const int w    = tid >> 6;      // wave 0..3
    const int lane = tid & 63;
    const int lrow = lane & 15;
    const int quad = lane >> 4;

    // ---- stage x tile: 4096 float4, 16 per thread, coalesced; cvt_pk packs ----
    {
        const float4* xg4 = (const float4*)(x + (size_t)row0 * Dn);
        #pragma unroll
        for (int i = 0; i < 16; ++i) {
            const int f = tid + i * 256;           // float4 idx 0..4095
            const float4 v = xg4[f];
            const int row = f >> 7, c4 = f & 127;  // 128 float4 per row
            const int kb = c4 >> 1, half = c4 & 1;
            uint2 o2;
            o2.x = cvt_pk_bf16(v.x, v.y);
            o2.y = cvt_pk_bf16(v.z, v.w);
            *(uint2*)(smem + ((row * 64 + (kb ^ (row & 7))) << 4) + (half << 3)) = o2;
        }
    }

    // ---- phase-1 weight prologue (no LDS dep): issue BEFORE the barrier ----
    const int ct0 = w * 4;
    bf16x8 aB[2][2], bB[2][5];
    #pragma unroll
    for (int p = 0; p < 2; ++p) {
        #pragma unroll
        for (int t = 0; t < 4; ++t)
            bB[p][t] = *(const bf16x8*)(W1f + ((((ct0 + t) * 16 + p) * 64 + lane) << 3));
        bB[p][4] = *(const bf16x8*)(Tf + (((w * 16 + p) * 64 + lane) << 3));
    }
    __syncthreads();

    // ---- phase 1: h1 = relu(x@W1+b1) (4 col tiles) + xt = x@thetas (1 tile) ----
    //      2 row-tiles per wave; prefetch distance 2 (full unroll, static idx).
    floatx4 acc[2][5];
    #pragma unroll
    for (int t = 0; t < 4; ++t) {
        const float bv = b1[(ct0 + t) * 16 + lrow];
        acc[0][t] = (floatx4){bv, bv, bv, bv};
        acc[1][t] = (floatx4){bv, bv, bv, bv};
    }
    acc[0][4] = (floatx4){0.f, 0.f, 0.f, 0.f};
    acc[1][4] = (floatx4){0.f, 0.f, 0.f, 0.f};

    #pragma unroll
    for (int p = 0; p < 2; ++p)
        #pragma unroll
        for (int rt = 0; rt < 2; ++rt)
            aB[p][rt] = *(const bf16x8*)(smem +
                (((rt * 16 + lrow) * 64 + ((p * 4 + quad) ^ (lrow & 7))) << 4));

    #pragma unroll
    for (int ks = 0; ks < 16; ++ks) {
        const int cur = ks & 1;
        #pragma unroll
        for (int t = 0; t < 5; ++t) {
            acc[0][t] = __builtin_amdgcn_mfma_f32_16x16x32_bf16(aB[cur][0], bB[cur][t], acc[0][t], 0, 0, 0);
            acc[1][t] = __builtin_amdgcn_mfma_f32_16x16x32_bf16(aB[cur][1], bB[cur][t], acc[1][t], 0, 0, 0);
        }
        if (ks < 14) {   // prefetch ks+2 into the slot just consumed
            const int kn = ks + 2;
            #pragma unroll
            for (int rt = 0; rt < 2; ++rt)
                aB[cur][rt] = *(const bf16x8*)(smem +
                    (((rt * 16 + lrow) * 64 + ((kn * 4 + quad) ^ (lrow & 7))) << 4));
            #pragma unroll
            for (int t = 0; t < 4; ++t)
                bB[cur][t] = *(const bf16x8*)(W1f + ((((ct0 + t) * 16 + kn) * 64 + lane) << 3));
            bB[cur][4] = *(const bf16x8*)(Tf + (((w * 16 + kn) * 64 + lane) << 3));
        }
    }
    __syncthreads();   // all xA reads complete -> @0 reusable for h1A

    // h1 C-layout -> bf16 A-layout @0 ; xt f32 -> @16384 [32][64] swizzled
    #pragma unroll
    for (int rt = 0; rt < 2; ++rt) {
        #pragma unroll
        for (int t = 0; t < 4; ++t) {
            const int col = (ct0 + t) * 16 + lrow;
            #pragma unroll
            for (int g = 0; g < 4; ++g) {
                const int orow = rt * 16 + quad * 4 + g;
                *(unsigned short*)(smem +
                    ((orow * 32 + ((col >> 3) ^ (orow & 7))) << 4) + ((col & 7) << 1))
                    = f2bf(fmaxf(acc[rt][t][g], 0.0f));
            }
        }
    }
    {
        float* xtf = (float*)(smem + 16384);
        const int xcol = (w * 16 + lrow) ^ (quad << 4);   // bank spread
        #pragma unroll
        for (int rt = 0; rt < 2; ++rt)
            #pragma unroll
            for (int g = 0; g < 4; ++g)
                xtf[(rt * 16 + quad * 4 + g) * 64 + xcol] = acc[rt][4][g];
    }

    // ---- phase-2 weight prologue + u/label prefetch: BEFORE the barrier ----
    const int c20 = w * 2;
    bf16x8 a2[2][2], b2B[2][2];
    #pragma unroll
    for (int p = 0; p < 2; ++p)
        #pragma unroll
        for (int i = 0; i < 2; ++i)
            b2B[p][i] = *(const bf16x8*)(W2f + ((((c20 + i) * 8 + p) * 64 + lane) << 3));
    float upf[8], labpf[8];
    #pragma unroll
    for (int rr = 0; rr < 8; ++rr) {
        upf[rr]   = u[(size_t)(row0 + w * 8 + rr) * Kn + lane];
        labpf[rr] = label[row0 + w * 8 + rr];
    }
    __syncthreads();   // h1A + xt ready

    // ---- h2 = relu(h1@W2+b2): 2 col tiles/wave x 2 row-tiles, dist-2 ----
    floatx4 acc2[2][2];
    #pragma unroll
    for (int i = 0; i < 2; ++i) {
        const float bv = b2[(c20 + i) * 16 + lrow];
        acc2[0][i] = (floatx4){bv, bv, bv, bv};
        acc2[1][i] = (floatx4){bv, bv, bv, bv};
    }
    #pragma unroll
    for (int p = 0; p < 2; ++p)
        #pragma unroll
        for (int rt = 0; rt < 2; ++rt)
            a2[p][rt] = *(const bf16x8*)(smem +
                (((rt * 16 + lrow) * 32 + ((p * 4 + quad) ^ (lrow & 7))) << 4));

    #pragma unroll
    for (int ks = 0; ks < 8; ++ks) {
        const int cur = ks & 1;
        #pragma unroll
        for (int i = 0; i < 2; ++i) {
            acc2[0][i] = __builtin_amdgcn_mfma_f32_16x16x32_bf16(a2[cur][0], b2B[cur][i], acc2[0][i], 0, 0, 0);
            acc2[1][i] = __builtin_amdgcn_mfma_f32_16x16x32_bf16(a2[cur][1], b2B[cur][i], acc2[1][i], 0, 0, 0);
        }
        if (ks < 6) {
            const int kn = ks + 2;
            #pragma unroll
            for (int rt = 0; rt < 2; ++rt)
                a2[cur][rt] = *(const bf16x8*)(smem +
                    (((rt * 16 + lrow) * 32 + ((kn * 4 + quad) ^ (lrow & 7))) << 4));
            #pragma unroll
            for (int i = 0; i < 2; ++i)
                b2B[cur][i] = *(const bf16x8*)(W2f + ((((c20 + i) * 8 + kn) * 64 + lane) << 3));
        }
    }
    // h2A @24576 (region dead since bar2; nobody reads it before next barrier)
    #pragma unroll
    for (int rt = 0; rt < 2; ++rt) {
        #pragma unroll
        for (int i = 0; i < 2; ++i) {
            const int col = (c20 + i) * 16 + lrow;
            #pragma unroll
            for (int g = 0; g < 4; ++g) {
                const int orow = rt * 16 + quad * 4 + g;
                *(unsigned short*)(smem + 24576 +
                    ((orow * 16 + ((col >> 3) ^ (orow & 7))) << 4) + ((col & 7) << 1))
                    = f2bf(fmaxf(acc2[rt][i][g], 0.0f));
            }
        }
    }

    // ---- phase-3 weight prologue: BEFORE the barrier ----
    bf16x8 bb[4];
    #pragma unroll
    for (int ks = 0; ks < 4; ++ks)
        bb[ks] = *(const bf16x8*)(W3f + (((w * 4 + ks) * 64 + lane) << 3));
    __syncthreads();   // h2A ready; h1A reads done -> @0 free for lg

    // ---- logits = h2@W3+b3: 1 col tile/wave x 2 row-tiles ----
    floatx4 acc3[2];
    {
        const float bv = b3[w * 16 + lrow];
        acc3[0] = (floatx4){bv, bv, bv, bv};
        acc3[1] = (floatx4){bv, bv, bv, bv};
    }
    {
        bf16x8 aa[2][4];
        #pragma unroll
        for (int ks = 0; ks < 4; ++ks)
            #pragma unroll
            for (int rt = 0; rt < 2; ++rt)
                aa[rt][ks] = *(const bf16x8*)(smem + 24576 +
                    (((rt * 16 + lrow) * 16 + ((ks * 4 + quad) ^ (lrow & 7))) << 4));
        #pragma unroll
        for (int ks = 0; ks < 4; ++ks)
            #pragma unroll
            for (int rt = 0; rt < 2; ++rt)
                acc3[rt] = __builtin_amdgcn_mfma_f32_16x16x32_bf16(aa[rt][ks], bb[ks], acc3[rt], 0, 0, 0);
    }
    {
        float* lgf = (float*)smem;   // [32][64] @0, swizzled like xt
        const int xcol = (w * 16 + lrow) ^ (quad << 4);
        #pragma unroll
        for (int rt = 0; rt < 2; ++rt)
            #pragma unroll
            for (int g = 0; g < 4; ++g)
                lgf[(rt * 16 + quad * 4 + g) * 64 + xcol] = acc3[rt][g];
    }
    __syncthreads();

    // ---- softmax + weighted sum + loss partial: wave w -> rows w*8..+7 ----
    {
        const float* lgf = (const float*)smem;
        const float* xtf = (const float*)(smem + 16384);
        const int ep = *epoch_p;
        const float tmp = 10.0f * powf(0.01f, (float)ep * 0.001f);
        const float inv_temp = 1.0f / fmaxf(0.1f, tmp);

        float partial = 0.0f;
        #pragma unroll
        for (int rr = 0; rr < 8; ++rr) {
            const int rw = w * 8 + rr;
            const int rlane = lane ^ ((rw & 12) << 2);   // un-swizzle
            const float g = -logf(-logf(upf[rr]));
            float s = (lgf[rw * 64 + rlane] + g) * inv_temp;
            float m = s;
            #pragma unroll
            for (int off = 32; off > 0; off >>= 1)
                m = fmaxf(m, __shfl_xor(m, off));
            const float e = expf(s - m);
            float sum = e;
            #pragma unroll
            for (int off = 32; off > 0; off >>= 1)
                sum += __shfl_xor(sum, off);
            float v = (e / sum) * xtf[rw * 64 + rlane];
            #pragma unroll
            for (int off = 32; off > 0; off >>= 1)
                v += __shfl_xor(v, off);
            const float diff = v - labpf[rr];   // same value on all lanes
            partial = fmaf(diff, diff, partial);
        }
        if (lane == 0)
            partials[blockIdx.x * 4 + w] = partial;   // private slot, no atomic
    }
}

extern "C" void kernel_launch(void* const* d_in, const int* in_sizes, int n_in,
                              void* d_out, int out_size, void* d_ws, size_t ws_size,
                              hipStream_t stream) {
    const float* x      = (const float*)d_in[0];
    const float* label  = (const float*)d_in[1];
    const float* u      = (const float*)d_in[2];
    const float* W1     = (const float*)d_in[3];
    const float* b1     = (const float*)d_in[4];
    const float* W2     = (const float*)d_in[5];
    const float* b2     = (const float*)d_in[6];
    const float* W3     = (const float*)d_in[7];
    const float* b3     = (const float*)d_in[8];
    const float* thetas = (const float*)d_in[9];
    const int*   epoch  = (const int*)d_in[10];
    float* out = (float*)d_out;

    unsigned short* wsb = (unsigned short*)d_ws;
    float* partials = (float*)((char*)d_ws + 409600);

    prep_k<<<800, 256, 0, stream>>>(W1, W2, W3, thetas, wsb);
    llp_mfma<<<Bn / BM, 256, 0, stream>>>(x, label, u, b1, b2, b3,
                                          wsb, wsb + 131072, wsb + 163840, wsb + 196608,
                                          epoch, partials);
    reduce_k<<<1, 1024, 0, stream>>>(partials, out);
}